// Round 18
// baseline (454.038 us; speedup 1.0000x reference)
//
#include <hip/hip_runtime.h>

// ---------------------------------------------------------------------------
// Round 18: R17 with the LDS layout bug fixed. R17 sized XsT as 2176 floats
// ("8704 B") but XsT is 8704 USHORTS = 17408 B = 4352 floats -> the staging
// writes overran WAp/WSp and the transform used clobbered weights (absmax
// 2e5). WAp now at smem+4352; SMEMF = 33792 B -> 4 blocks/CU.
// Kept from R17: register-held dual-direction partition (edge arrays read
// once, 16 edges/thread in VGPRs, both dirs through one 32 KB staging), and
// bf16-packed W in transform LDS (40 B LDS per 64 FLOP).
// ---------------------------------------------------------------------------

#define CHP 4096  // edges per partition block (both directions)
#define BC 6144   // bucket capacity (E[cnt]=5120, sigma=72 -> 14-sigma margin)

__device__ __forceinline__ float b2f(unsigned short u) {
    union { unsigned int i; float f; } v; v.i = ((unsigned int)u) << 16; return v.f;
}
__device__ __forceinline__ unsigned short f2b(float f) {
    union { float f; unsigned int i; } v; v.f = f;
    unsigned int i = v.i;
    return (unsigned short)((i + 0x7FFFu + ((i >> 16) & 1u)) >> 16);  // RNE
}
__device__ __forceinline__ float2 bf2(unsigned int w) {   // unpack 2 bf16
    union { unsigned int i; float f; } lo, hi;
    lo.i = w << 16; hi.i = w & 0xFFFF0000u;
    return make_float2(lo.f, hi.f);
}
__device__ __forceinline__ unsigned int pk2(float a, float b) {
    return (unsigned int)f2b(a) | ((unsigned int)f2b(b) << 16);
}

// ---- build_a: [0,np) dual-dir partition | movie_init | wt | user cvt ------

__global__ __launch_bounds__(256) void build_a(
    int np,
    const int* __restrict__ src, const int* __restrict__ dst, int E,
    int nbu, int nbm, int* __restrict__ bfu, int* __restrict__ bfm,
    int* __restrict__ pu, int* __restrict__ pm,
    const float* __restrict__ movie_x, const float* __restrict__ wm,
    const float* __restrict__ bm, const float* __restrict__ memb,
    unsigned short* __restrict__ xmB, int M,
    const float* __restrict__ llw, const float* __restrict__ lrw,
    float* __restrict__ wTl, float* __restrict__ wTr,
    const float* __restrict__ uemb, unsigned short* __restrict__ buB, int n4u) {
    __shared__ int2 stag[CHP];           // 32 KB ordered staging (per direction)
    __shared__ int hist[512];
    __shared__ int scn[512];
    __shared__ int gb[400];
    __shared__ int lst[400];
    int t = threadIdx.x;
    int b = blockIdx.x;
    if (b < np) {
        // ---- one chunk, both directions; edges held in registers ----
        int c0 = b * CHP, lim = min(c0 + CHP, E), cnt = lim - c0;
        int ks[16], vs[16];
#pragma unroll
        for (int i = 0; i < 16; ++i) {
            int e = c0 + t + i * 256;
            if (e < lim) { ks[i] = src[e]; vs[i] = dst[e]; }
            else { ks[i] = 0; vs[i] = 0; }
        }
        for (int dir = 0; dir < 2; ++dir) {
            const int NB = dir ? nbm : nbu;
            const int SHIFT = dir ? 7 : 8;
            int* bf = dir ? bfm : bfu;
            int* P  = dir ? pm  : pu;
            __syncthreads();   // protect stag/hist reuse from previous dir
            for (int i = t; i < 512; i += 256) hist[i] = 0;
            __syncthreads();
#pragma unroll
            for (int i = 0; i < 16; ++i) {
                if (t + i * 256 < cnt) {
                    int k = dir ? vs[i] : ks[i];
                    atomicAdd(&hist[k >> SHIFT], 1);
                }
            }
            __syncthreads();
            scn[t] = hist[t]; scn[t + 256] = hist[t + 256];
            __syncthreads();
            for (int off = 1; off < 512; off <<= 1) {
                int v0 = scn[t],  a0 = (t >= off) ? scn[t - off] : 0;
                int i1 = t + 256;
                int v1 = scn[i1], a1 = scn[i1 - off];
                __syncthreads();
                scn[t] = v0 + a0; scn[i1] = v1 + a1;
                __syncthreads();
            }
            for (int i = t; i < NB; i += 256) {
                int c = hist[i];
                lst[i] = scn[i] - c;
                int r = c ? atomicAdd(&bf[i], c) : 0;
                if (r < 0) r = 0;
                if (r + c > BC) r = BC - c;
                gb[i] = i * BC + r;
            }
            __syncthreads();
            for (int i = t; i < 512; i += 256) hist[i] = (i < NB) ? lst[i] : 0;
            __syncthreads();
#pragma unroll
            for (int i = 0; i < 16; ++i) {
                if (t + i * 256 < cnt) {
                    int k = dir ? vs[i] : ks[i];
                    int v = dir ? ks[i] : vs[i];
                    int bk = k >> SHIFT;
                    int pos = atomicAdd(&hist[bk], 1);
                    int packed = dir ? ((v << 7) | (k & 127)) : ((v << 8) | (k & 255));
                    stag[pos] = make_int2(packed, bk);
                }
            }
            __syncthreads();
            for (int j = t; j < cnt; j += 256) {
                int2 s = stag[j];
                P[gb[s.y] + (j - lst[s.y])] = s.x;
            }
        }
        return;
    }
    int lb = b - np;
    if (lb < 1024) {
        float* w_s = (float*)stag;   // 64*21 floats
        for (int i = t; i < 64 * 20; i += 256) {
            int h = i / 20, f = i % 20;
            w_s[h * 21 + f] = wm[i];
        }
        __syncthreads();
        int lane = t & 63;
        float bias = bm[lane];
        int nw = (1024 * 256) >> 6;
        int w  = (lb * 256 + t) >> 6;
        for (int m = w; m < M; m += nw) {
            float fv  = (lane < 20) ? movie_x[m * 20 + lane] : 0.0f;
            float acc = bias + memb[m * 64 + lane];
#pragma unroll
            for (int f = 0; f < 20; ++f) {
                float xv = __shfl(fv, f, 64);
                acc += xv * w_s[lane * 21 + f];
            }
            xmB[m * 64 + lane] = f2b(acc);
        }
    } else if (lb < 1088) {
        int i = (lb - 1024) * 256 + t;
        int s = i >> 12, rem = i & 4095, k = rem >> 6, h = rem & 63;
        wTl[i] = llw[s * 4096 + h * 64 + k];
        wTr[i] = lrw[s * 4096 + h * 64 + k];
    } else {
        int i0 = ((lb - 1088) * 256 + t) * 4;
#pragma unroll
        for (int k = 0; k < 4; ++k) {
            int i = i0 + k;
            if (i < n4u) {
                float4 v = ((const float4*)uemb)[i];
                ushort4 o;
                o.x = f2b(v.x); o.y = f2b(v.y); o.z = f2b(v.z); o.w = f2b(v.w);
                ((ushort4*)buB)[i] = o;
            }
        }
    }
}

// ---- transform tiles: 128-node tiles, 4x8/thread, XsT bf16, W bf16-packed -
// LDS floats: XsT uint[64][68] = 4352 | WAp uint[2048] | WSp uint[2048]

__device__ __forceinline__ void transform_tiles(
    int tile0, int stride, int ntiles,
    unsigned short* XsT, unsigned int* WAp, unsigned int* WSp,
    const unsigned short* __restrict__ X, const float* __restrict__ wA,
    const float* __restrict__ wS, const float* __restrict__ bS,
    unsigned short* __restrict__ A, unsigned short* __restrict__ S, int n) {
    int tid = threadIdx.x;
    for (int i = tid; i < 2048; i += 256) {
        WAp[i] = pk2(wA[2 * i], wA[2 * i + 1]);   // [k][hpair] packed
        WSp[i] = pk2(wS[2 * i], wS[2 * i + 1]);
    }
    int hg = tid & 7, ng = tid >> 3;       // 8 col-groups x 32 row-groups
    int h0 = hg * 8, nA = ng * 4;
    float4 b0 = *(const float4*)&bS[h0];
    float4 b1 = *(const float4*)&bS[h0 + 4];
    float bias[8] = {b0.x, b0.y, b0.z, b0.w, b1.x, b1.y, b1.z, b1.w};
    unsigned int* XsT32 = (unsigned int*)XsT;   // pitch 68 uints per k row

    for (int tile = tile0; tile < ntiles; tile += stride) {
        int node0 = tile * 128;
        __syncthreads();   // prev-iter reads done; W visible on first iter
        for (int it = tid; it < 512; it += 256) {
            int p = it & 63, c = it >> 6;
            int g0 = node0 + 2 * p, g1 = g0 + 1;
            uint4 av = make_uint4(0, 0, 0, 0), bv = make_uint4(0, 0, 0, 0);
            if (g0 < n) av = *(const uint4*)(X + (size_t)g0 * 64 + c * 8);
            if (g1 < n) bv = *(const uint4*)(X + (size_t)g1 * 64 + c * 8);
            unsigned int aw[4] = {av.x, av.y, av.z, av.w};
            unsigned int bw[4] = {bv.x, bv.y, bv.z, bv.w};
#pragma unroll
            for (int j = 0; j < 8; ++j) {
                int w = j >> 1;
                unsigned int o = (j & 1)
                    ? ((aw[w] >> 16) | (bw[w] & 0xFFFF0000u))
                    : ((aw[w] & 0xFFFFu) | (bw[w] << 16));
                XsT32[(c * 8 + j) * 68 + p] = o;
            }
        }
        __syncthreads();
        float accA[4][8], accS[4][8];
#pragma unroll
        for (int r = 0; r < 4; ++r)
#pragma unroll
            for (int c = 0; c < 8; ++c) { accA[r][c] = 0.0f; accS[r][c] = 0.0f; }
#pragma unroll 4
        for (int k = 0; k < 64; ++k) {
            ushort4 xv = *(const ushort4*)(XsT + k * 136 + nA);
            float xr[4] = {b2f(xv.x), b2f(xv.y), b2f(xv.z), b2f(xv.w)};
            uint4 aw = *(const uint4*)&WAp[k * 32 + hg * 4];
            uint4 sw = *(const uint4*)&WSp[k * 32 + hg * 4];
            float2 a0 = bf2(aw.x), a1 = bf2(aw.y), a2 = bf2(aw.z), a3 = bf2(aw.w);
            float2 s0 = bf2(sw.x), s1 = bf2(sw.y), s2 = bf2(sw.z), s3 = bf2(sw.w);
            float wa[8] = {a0.x, a0.y, a1.x, a1.y, a2.x, a2.y, a3.x, a3.y};
            float ws[8] = {s0.x, s0.y, s1.x, s1.y, s2.x, s2.y, s3.x, s3.y};
#pragma unroll
            for (int r = 0; r < 4; ++r)
#pragma unroll
                for (int c = 0; c < 8; ++c) {
                    accA[r][c] += xr[r] * wa[c];
                    accS[r][c] += xr[r] * ws[c];
                }
        }
#pragma unroll
        for (int r = 0; r < 4; ++r) {
            int gi = node0 + nA + r;
            if (gi < n) {
                uint4 oa, os;
                oa.x = pk2(accA[r][0], accA[r][1]); oa.y = pk2(accA[r][2], accA[r][3]);
                oa.z = pk2(accA[r][4], accA[r][5]); oa.w = pk2(accA[r][6], accA[r][7]);
                os.x = pk2(accS[r][0] + bias[0], accS[r][1] + bias[1]);
                os.y = pk2(accS[r][2] + bias[2], accS[r][3] + bias[3]);
                os.z = pk2(accS[r][4] + bias[4], accS[r][5] + bias[5]);
                os.w = pk2(accS[r][6] + bias[6], accS[r][7] + bias[7]);
                *(uint4*)(A + (size_t)gi * 64 + h0) = oa;
                *(uint4*)(S + (size_t)gi * 64 + h0) = os;
            }
        }
    }
}

// ---- fine CSR body --------------------------------------------------------

template <int NPB, int SH, typename CT>
__device__ __forceinline__ void fine_body(
    int b, int* c, int* sc, const int* __restrict__ part,
    const int* __restrict__ cnt_arr,
    int2* __restrict__ rp2, CT* __restrict__ col, int n) {
    int cnt = min(cnt_arr[b], BC);
    int pb = b * BC;
    int t = threadIdx.x;
    c[t] = 0;
    __syncthreads();
    const int mask = NPB - 1;
    for (int j = t; j < cnt; j += 256)
        atomicAdd(&c[part[pb + j] & mask], 1);
    __syncthreads();
    int own = c[t];
    sc[t] = own;
    __syncthreads();
    for (int off = 1; off < 256; off <<= 1) {
        int val = sc[t];
        int add = (t >= off) ? sc[t - off] : 0;
        __syncthreads();
        sc[t] = val + add;
        __syncthreads();
    }
    int start = pb + sc[t] - own;
    int node = b * NPB + t;
    if (t < NPB && node < n) rp2[node] = make_int2(start, start + own);
    __syncthreads();
    c[t] = start;
    __syncthreads();
    for (int j = t; j < cnt; j += 256) {
        int p = part[pb + j];
        int off = atomicAdd(&c[p & mask], 1);
        col[off] = (CT)(((unsigned)p) >> SH);
    }
}

#define TBM 256   // movie transform blocks
#define TBU 512   // user transform blocks
#define SMEMF (4352 + 2048 + 2048)   // floats: XsT 17408 B + WAp 8 KB + WSp 8 KB = 33792 B

// ---- build_b: [0, nbm+nbu) fine CSR | +TBM movie transform | +TBU user ----

__global__ __launch_bounds__(256) void build_b(
    int nbm, int nbu, int ntm, int ntu,
    const int* __restrict__ pm, const int* __restrict__ cm,
    int2* __restrict__ rp2_m, int* __restrict__ col_m, int M,
    const int* __restrict__ pu, const int* __restrict__ cu,
    int2* __restrict__ rp2_u, unsigned short* __restrict__ col_u, int U,
    const unsigned short* __restrict__ xM, const float* __restrict__ wAM,
    const float* __restrict__ wSM, const float* __restrict__ bSM,
    unsigned short* __restrict__ AM, unsigned short* __restrict__ SM,
    const unsigned short* __restrict__ xU, const float* __restrict__ wAU,
    const float* __restrict__ wSU, const float* __restrict__ bSU,
    unsigned short* __restrict__ AU, unsigned short* __restrict__ SU) {
    __shared__ float smem[SMEMF];
    int b = blockIdx.x;
    if (b < nbm) {
        fine_body<128, 7, int>(b, (int*)smem, (int*)smem + 256, pm, cm, rp2_m, col_m, M);
        return;
    }
    b -= nbm;
    if (b < nbu) {
        fine_body<256, 8, unsigned short>(b, (int*)smem, (int*)smem + 256, pu, cu, rp2_u, col_u, U);
        return;
    }
    b -= nbu;
    unsigned short* XsT = (unsigned short*)smem;
    unsigned int* WAp = (unsigned int*)(smem + 4352);
    unsigned int* WSp = WAp + 2048;
    if (b < TBM) transform_tiles(b, TBM, ntm, XsT, WAp, WSp, xM, wAM, wSM, bSM, AM, SM, M);
    else transform_tiles(b - TBM, TBU, ntu, XsT, WAp, WSp, xU, wAU, wSU, bSU, AU, SU, U);
}

// ---- standalone transform (layer 1) ---------------------------------------

__global__ __launch_bounds__(256) void transform_dual(
    int ntm, int ntu,
    const unsigned short* __restrict__ xM, const float* __restrict__ wAM,
    const float* __restrict__ wSM, const float* __restrict__ bSM,
    unsigned short* __restrict__ AM, unsigned short* __restrict__ SM, int M,
    const unsigned short* __restrict__ xU, const float* __restrict__ wAU,
    const float* __restrict__ wSU, const float* __restrict__ bSU,
    unsigned short* __restrict__ AU, unsigned short* __restrict__ SU, int U) {
    __shared__ float smem[SMEMF];
    unsigned short* XsT = (unsigned short*)smem;
    unsigned int* WAp = (unsigned int*)(smem + 4352);
    unsigned int* WSp = WAp + 2048;
    int b = blockIdx.x;
    if (b < TBM) transform_tiles(b, TBM, ntm, XsT, WAp, WSp, xM, wAM, wSM, bSM, AM, SM, M);
    else transform_tiles(b - TBM, TBU, ntu, XsT, WAp, WSp, xU, wAU, wSU, bSU, AU, SU, U);
}

// ---- dual gather: 8 groups x 8 lanes, uint4 rows --------------------------

template <typename CT>
__device__ __forceinline__ void gather_body(
    int b, const int2* __restrict__ rp2, const CT* __restrict__ col,
    const unsigned short* __restrict__ A, const unsigned short* __restrict__ S,
    unsigned short* __restrict__ out, int n, int do_relu) {
    int node = (b * 256 + threadIdx.x) >> 6;
    if (node >= n) return;
    int lane = threadIdx.x & 63;
    int g = lane >> 3, q = lane & 7;     // 8 neighbor-groups x 8 feature-lanes
    int2 be = rp2[node];
    int beg = be.x, end = be.y;
    float s0 = 0, s1 = 0, s2 = 0, s3 = 0, s4 = 0, s5 = 0, s6 = 0, s7 = 0;
    float t0 = 0, t1 = 0, t2 = 0, t3 = 0, t4 = 0, t5 = 0, t6 = 0, t7 = 0;
    int j = beg + g;
    for (; j + 8 < end; j += 16) {
        int n0 = (int)col[j], n1 = (int)col[j + 8];
        uint4 w0 = *(const uint4*)(A + (size_t)n0 * 64 + q * 8);
        uint4 w1 = *(const uint4*)(A + (size_t)n1 * 64 + q * 8);
        float2 p;
        p = bf2(w0.x); s0 += p.x; s1 += p.y;
        p = bf2(w0.y); s2 += p.x; s3 += p.y;
        p = bf2(w0.z); s4 += p.x; s5 += p.y;
        p = bf2(w0.w); s6 += p.x; s7 += p.y;
        p = bf2(w1.x); t0 += p.x; t1 += p.y;
        p = bf2(w1.y); t2 += p.x; t3 += p.y;
        p = bf2(w1.z); t4 += p.x; t5 += p.y;
        p = bf2(w1.w); t6 += p.x; t7 += p.y;
    }
    if (j < end) {
        int n0 = (int)col[j];
        uint4 w0 = *(const uint4*)(A + (size_t)n0 * 64 + q * 8);
        float2 p;
        p = bf2(w0.x); s0 += p.x; s1 += p.y;
        p = bf2(w0.y); s2 += p.x; s3 += p.y;
        p = bf2(w0.z); s4 += p.x; s5 += p.y;
        p = bf2(w0.w); s6 += p.x; s7 += p.y;
    }
    s0 += t0; s1 += t1; s2 += t2; s3 += t3;
    s4 += t4; s5 += t5; s6 += t6; s7 += t7;
#pragma unroll
    for (int off = 8; off < 64; off <<= 1) {
        s0 += __shfl_xor(s0, off, 64); s1 += __shfl_xor(s1, off, 64);
        s2 += __shfl_xor(s2, off, 64); s3 += __shfl_xor(s3, off, 64);
        s4 += __shfl_xor(s4, off, 64); s5 += __shfl_xor(s5, off, 64);
        s6 += __shfl_xor(s6, off, 64); s7 += __shfl_xor(s7, off, 64);
    }
    if (g == 0) {
        float inv = 1.0f / fmaxf((float)(end - beg), 1.0f);
        uint4 sv = *(const uint4*)(S + (size_t)node * 64 + q * 8);
        float2 c0 = bf2(sv.x), c1 = bf2(sv.y), c2 = bf2(sv.z), c3 = bf2(sv.w);
        float v0 = s0 * inv + c0.x, v1 = s1 * inv + c0.y;
        float v2 = s2 * inv + c1.x, v3 = s3 * inv + c1.y;
        float v4 = s4 * inv + c2.x, v5 = s5 * inv + c2.y;
        float v6 = s6 * inv + c3.x, v7 = s7 * inv + c3.y;
        if (do_relu) {
            v0 = fmaxf(v0, 0.f); v1 = fmaxf(v1, 0.f); v2 = fmaxf(v2, 0.f);
            v3 = fmaxf(v3, 0.f); v4 = fmaxf(v4, 0.f); v5 = fmaxf(v5, 0.f);
            v6 = fmaxf(v6, 0.f); v7 = fmaxf(v7, 0.f);
        }
        uint4 o;
        o.x = pk2(v0, v1); o.y = pk2(v2, v3); o.z = pk2(v4, v5); o.w = pk2(v6, v7);
        *(uint4*)(out + (size_t)node * 64 + q * 8) = o;
    }
}

__global__ __launch_bounds__(256) void gather_dual(
    int gm,
    const int2* __restrict__ rp2_m, const int* __restrict__ col_m,
    const unsigned short* __restrict__ AU, const unsigned short* __restrict__ SM,
    unsigned short* __restrict__ outM, int M,
    const int2* __restrict__ rp2_u, const unsigned short* __restrict__ col_u,
    const unsigned short* __restrict__ AM, const unsigned short* __restrict__ SU,
    unsigned short* __restrict__ outU, int U, int do_relu) {
    int b = blockIdx.x;
    if (b < gm) gather_body<int>(b, rp2_m, col_m, AU, SM, outM, M, do_relu);
    else gather_body<unsigned short>(b - gm, rp2_u, col_u, AM, SU, outU, U, do_relu);
}

// ---- link head: 8 edges/wave, uint4 lanes ---------------------------------

__global__ __launch_bounds__(256) void dot_bf16(
    const int* __restrict__ ls, const int* __restrict__ ld,
    const unsigned short* __restrict__ xuB, const unsigned short* __restrict__ xmB,
    float* __restrict__ out, int L) {
    int t = blockIdx.x * 256 + threadIdx.x;
    int lane = t & 63;
    int sub = lane >> 3, q = lane & 7;
    int e = (t >> 6) * 8 + sub;
    if (e < L) {
        int u = ls[e], m = ld[e];
        uint4 a = *(const uint4*)(xuB + (size_t)u * 64 + q * 8);
        uint4 b = *(const uint4*)(xmB + (size_t)m * 64 + q * 8);
        float2 a0 = bf2(a.x), a1 = bf2(a.y), a2 = bf2(a.z), a3 = bf2(a.w);
        float2 b0 = bf2(b.x), b1 = bf2(b.y), b2 = bf2(b.z), b3 = bf2(b.w);
        float p = a0.x * b0.x + a0.y * b0.y + a1.x * b1.x + a1.y * b1.y
                + a2.x * b2.x + a2.y * b2.y + a3.x * b3.x + a3.y * b3.y;
#pragma unroll
        for (int off = 1; off < 8; off <<= 1) p += __shfl_xor(p, off, 64);
        if (q == 0) out[e] = p;
    }
}

// ---------------------------------------------------------------------------

extern "C" void kernel_launch(void* const* d_in, const int* in_sizes, int n_in,
                              void* d_out, int out_size, void* d_ws, size_t ws_size,
                              hipStream_t stream) {
    const float* movie_x   = (const float*)d_in[0];
    const float* user_emb  = (const float*)d_in[1];
    const float* movie_emb = (const float*)d_in[2];
    const float* mlw       = (const float*)d_in[3];
    const float* mlb       = (const float*)d_in[4];
    const float* llw       = (const float*)d_in[5];   // [2][2][64][64]
    const float* llb       = (const float*)d_in[6];   // [2][2][64]
    const float* lrw       = (const float*)d_in[7];   // [2][2][64][64]
    const int*   esrc      = (const int*)d_in[8];
    const int*   edst      = (const int*)d_in[9];
    const int*   lsrc      = (const int*)d_in[10];
    const int*   ldst      = (const int*)d_in[11];

    const int U = in_sizes[1] / 64;
    const int M = in_sizes[2] / 64;
    const int E = in_sizes[8];
    const int L = in_sizes[10];
    float* out = (float*)d_out;

    const size_t M64 = (size_t)M * 64, U64 = (size_t)U * 64;
    const int nbu = (U + 255) >> 8;   // 256-user buckets  (391)
    const int nbm = (M + 127) >> 7;   // 128-movie buckets (391)

    // ---- ws layout: 256 B-aligned regions, hot tables first ----
    char* base = (char*)d_ws;
    size_t off = 0;
    auto alloc = [&](size_t bytes) -> void* {
        off = (off + 255) & ~(size_t)255;
        void* p = base + off;
        off += bytes;
        return p;
    };
    unsigned short* bmB0 = (unsigned short*)alloc(M64 * 2);   // movie feat L0 bf16
    unsigned short* buB0 = (unsigned short*)alloc(U64 * 2);   // user feat L0 bf16
    unsigned short* A_m  = (unsigned short*)alloc(M64 * 2);   // bf16, gathered by users
    unsigned short* A_u  = (unsigned short*)alloc(U64 * 2);   // bf16, gathered by movies
    unsigned short* S_m  = (unsigned short*)alloc(M64 * 2);   // bf16 self term
    unsigned short* S_u  = (unsigned short*)alloc(U64 * 2);
    unsigned short* xm1  = (unsigned short*)alloc(M64 * 2);   // layer-0 movie out
    unsigned short* xu1  = (unsigned short*)alloc(U64 * 2);   // layer-0 user out
    float* wTl = (float*)alloc(4 * 4096 * 4);
    float* wTr = (float*)alloc(4 * 4096 * 4);
    int2* rp2_m = (int2*)alloc((size_t)M * 8);
    int2* rp2_u = (int2*)alloc((size_t)U * 8);
    int* col_m = (int*)alloc((size_t)nbm * BC * 4);           // padded, user ids
    unsigned short* col_u = (unsigned short*)alloc((size_t)nbu * BC * 2);
    int* bfu = (int*)alloc(800 * 4);                          // ONE region: bfu|bfm
    int* bfm = bfu + 400;
    int* part_u = (int*)alloc((size_t)nbu * BC * 4);          // packed 24-bit
    int* part_m = (int*)alloc((size_t)nbm * BC * 4);
    // final tables alias the (dead-by-then) part buffers (contiguous, aligned):
    unsigned short* xm2 = (unsigned short*)part_u;            // [M,64] final movie
    unsigned short* xu2 = xm2 + M64;                          // [U,64] final user

    const int np    = (E + CHP - 1) / CHP;                    // dual-dir chunks
    const int cvtb  = (U * 16 / 4 + 255) / 256;               // 4 float4/thread
    const int ntm = (M + 127) / 128, ntu = (U + 127) / 128;   // 128-node tiles
    const int gm_g = (M * 64 + 255) / 256, gu_g = (U * 64 + 255) / 256;

    // ---- build_a: dual-dir register partition + prep (fused) ----
    hipMemsetAsync(bfu, 0, 800 * sizeof(int), stream);
    build_a<<<np + 1088 + cvtb, 256, 0, stream>>>(
        np, esrc, edst, E, nbu, nbm, bfu, bfm, part_u, part_m,
        movie_x, mlw, mlb, movie_emb, bmB0, M,
        llw, lrw, wTl, wTr, user_emb, buB0, U * 16);

    // ---- build_b: fine CSR + transform L0 (fused) ----
    build_b<<<nbm + nbu + TBM + TBU, 256, 0, stream>>>(
        nbm, nbu, ntm, ntu,
        part_m, bfm, rp2_m, col_m, M,
        part_u, bfu, rp2_u, col_u, U,
        bmB0, wTl + 1 * 4096, wTr + 0 * 4096, llb + 0 * 64, A_m, S_m,
        buB0, wTl + 0 * 4096, wTr + 1 * 4096, llb + 1 * 64, A_u, S_u);

    // ---- layer 0 gather ----
    gather_dual<<<gm_g + gu_g, 256, 0, stream>>>(gm_g,
        rp2_m, col_m, A_u, S_m, xm1, M,
        rp2_u, col_u, A_m, S_u, xu1, U, 1);

    // ---- layer 1 ---- (A/S reused; part buffers now dead -> xm2/xu2)
    transform_dual<<<TBM + TBU, 256, 0, stream>>>(ntm, ntu,
        xm1, wTl + 3 * 4096, wTr + 2 * 4096, llb + 2 * 64, A_m, S_m, M,
        xu1, wTl + 2 * 4096, wTr + 3 * 4096, llb + 3 * 64, A_u, S_u, U);
    gather_dual<<<gm_g + gu_g, 256, 0, stream>>>(gm_g,
        rp2_m, col_m, A_u, S_m, xm2, M,
        rp2_u, col_u, A_m, S_u, xu2, U, 0);

    // ---- link head ----
    dot_bf16<<<(L + 31) / 32, 256, 0, stream>>>(lsrc, ldst, xu2, xm2, out, L);
}

// Round 19
// 437.005 us; speedup vs baseline: 1.0390x; 1.0390x over previous
//
#include <hip/hip_runtime.h>

// ---------------------------------------------------------------------------
// Round 19: cherry-pick of measured-best halves.
//  - build_a: R18's register-held dual-direction partition (edge arrays read
//    once; 16 edges/thread in VGPRs; both dirs via one 32 KB LDS staging).
//  - transform: R16's fp32-W-in-LDS version (float4 W reads, no bf16 unpack
//    in the k-loop) — R18's packed-W variant cost ~5 us of extra VALU.
//  - gather (6.2 TB/s fabric ceiling), dot, fine CSR unchanged.
// absmax expected back at 0.078125 (fp32 weights).
// ---------------------------------------------------------------------------

#define CHP 4096  // edges per partition block (both directions)
#define BC 6144   // bucket capacity (E[cnt]=5120, sigma=72 -> 14-sigma margin)

__device__ __forceinline__ float b2f(unsigned short u) {
    union { unsigned int i; float f; } v; v.i = ((unsigned int)u) << 16; return v.f;
}
__device__ __forceinline__ unsigned short f2b(float f) {
    union { float f; unsigned int i; } v; v.f = f;
    unsigned int i = v.i;
    return (unsigned short)((i + 0x7FFFu + ((i >> 16) & 1u)) >> 16);  // RNE
}
__device__ __forceinline__ float2 bf2(unsigned int w) {   // unpack 2 bf16
    union { unsigned int i; float f; } lo, hi;
    lo.i = w << 16; hi.i = w & 0xFFFF0000u;
    return make_float2(lo.f, hi.f);
}
__device__ __forceinline__ unsigned int pk2(float a, float b) {
    return (unsigned int)f2b(a) | ((unsigned int)f2b(b) << 16);
}

// ---- build_a: [0,np) dual-dir partition | movie_init | wt | user cvt ------

__global__ __launch_bounds__(256) void build_a(
    int np,
    const int* __restrict__ src, const int* __restrict__ dst, int E,
    int nbu, int nbm, int* __restrict__ bfu, int* __restrict__ bfm,
    int* __restrict__ pu, int* __restrict__ pm,
    const float* __restrict__ movie_x, const float* __restrict__ wm,
    const float* __restrict__ bm, const float* __restrict__ memb,
    unsigned short* __restrict__ xmB, int M,
    const float* __restrict__ llw, const float* __restrict__ lrw,
    float* __restrict__ wTl, float* __restrict__ wTr,
    const float* __restrict__ uemb, unsigned short* __restrict__ buB, int n4u) {
    __shared__ int2 stag[CHP];           // 32 KB ordered staging (per direction)
    __shared__ int hist[512];
    __shared__ int scn[512];
    __shared__ int gb[400];
    __shared__ int lst[400];
    int t = threadIdx.x;
    int b = blockIdx.x;
    if (b < np) {
        // ---- one chunk, both directions; edges held in registers ----
        int c0 = b * CHP, lim = min(c0 + CHP, E), cnt = lim - c0;
        int ks[16], vs[16];
#pragma unroll
        for (int i = 0; i < 16; ++i) {
            int e = c0 + t + i * 256;
            if (e < lim) { ks[i] = src[e]; vs[i] = dst[e]; }
            else { ks[i] = 0; vs[i] = 0; }
        }
        for (int dir = 0; dir < 2; ++dir) {
            const int NB = dir ? nbm : nbu;
            const int SHIFT = dir ? 7 : 8;
            int* bf = dir ? bfm : bfu;
            int* P  = dir ? pm  : pu;
            __syncthreads();   // protect stag/hist reuse from previous dir
            for (int i = t; i < 512; i += 256) hist[i] = 0;
            __syncthreads();
#pragma unroll
            for (int i = 0; i < 16; ++i) {
                if (t + i * 256 < cnt) {
                    int k = dir ? vs[i] : ks[i];
                    atomicAdd(&hist[k >> SHIFT], 1);
                }
            }
            __syncthreads();
            scn[t] = hist[t]; scn[t + 256] = hist[t + 256];
            __syncthreads();
            for (int off = 1; off < 512; off <<= 1) {
                int v0 = scn[t],  a0 = (t >= off) ? scn[t - off] : 0;
                int i1 = t + 256;
                int v1 = scn[i1], a1 = scn[i1 - off];
                __syncthreads();
                scn[t] = v0 + a0; scn[i1] = v1 + a1;
                __syncthreads();
            }
            for (int i = t; i < NB; i += 256) {
                int c = hist[i];
                lst[i] = scn[i] - c;
                int r = c ? atomicAdd(&bf[i], c) : 0;
                if (r < 0) r = 0;
                if (r + c > BC) r = BC - c;
                gb[i] = i * BC + r;
            }
            __syncthreads();
            for (int i = t; i < 512; i += 256) hist[i] = (i < NB) ? lst[i] : 0;
            __syncthreads();
#pragma unroll
            for (int i = 0; i < 16; ++i) {
                if (t + i * 256 < cnt) {
                    int k = dir ? vs[i] : ks[i];
                    int v = dir ? ks[i] : vs[i];
                    int bk = k >> SHIFT;
                    int pos = atomicAdd(&hist[bk], 1);
                    int packed = dir ? ((v << 7) | (k & 127)) : ((v << 8) | (k & 255));
                    stag[pos] = make_int2(packed, bk);
                }
            }
            __syncthreads();
            for (int j = t; j < cnt; j += 256) {
                int2 s = stag[j];
                P[gb[s.y] + (j - lst[s.y])] = s.x;
            }
        }
        return;
    }
    int lb = b - np;
    if (lb < 1024) {
        float* w_s = (float*)stag;   // 64*21 floats
        for (int i = t; i < 64 * 20; i += 256) {
            int h = i / 20, f = i % 20;
            w_s[h * 21 + f] = wm[i];
        }
        __syncthreads();
        int lane = t & 63;
        float bias = bm[lane];
        int nw = (1024 * 256) >> 6;
        int w  = (lb * 256 + t) >> 6;
        for (int m = w; m < M; m += nw) {
            float fv  = (lane < 20) ? movie_x[m * 20 + lane] : 0.0f;
            float acc = bias + memb[m * 64 + lane];
#pragma unroll
            for (int f = 0; f < 20; ++f) {
                float xv = __shfl(fv, f, 64);
                acc += xv * w_s[lane * 21 + f];
            }
            xmB[m * 64 + lane] = f2b(acc);
        }
    } else if (lb < 1088) {
        int i = (lb - 1024) * 256 + t;
        int s = i >> 12, rem = i & 4095, k = rem >> 6, h = rem & 63;
        wTl[i] = llw[s * 4096 + h * 64 + k];
        wTr[i] = lrw[s * 4096 + h * 64 + k];
    } else {
        int i0 = ((lb - 1088) * 256 + t) * 4;
#pragma unroll
        for (int k = 0; k < 4; ++k) {
            int i = i0 + k;
            if (i < n4u) {
                float4 v = ((const float4*)uemb)[i];
                ushort4 o;
                o.x = f2b(v.x); o.y = f2b(v.y); o.z = f2b(v.z); o.w = f2b(v.w);
                ((ushort4*)buB)[i] = o;
            }
        }
    }
}

// ---- transform tiles: 128-node tiles, 4x8/thread, XsT bf16, W fp32 in LDS -
// LDS floats: XsT uint[64][68] = 4352 | WA[4096] | WS[4096]  (50176 B)

__device__ __forceinline__ void transform_tiles(
    int tile0, int stride, int ntiles,
    unsigned short* XsT, float* WA, float* WS,
    const unsigned short* __restrict__ X, const float* __restrict__ wA,
    const float* __restrict__ wS, const float* __restrict__ bS,
    unsigned short* __restrict__ A, unsigned short* __restrict__ S, int n) {
    int tid = threadIdx.x;
    for (int i = tid; i < 4096; i += 256) { WA[i] = wA[i]; WS[i] = wS[i]; }
    int hg = tid & 7, ng = tid >> 3;       // 8 col-groups x 32 row-groups
    int h0 = hg * 8, nA = ng * 4;
    float4 b0 = *(const float4*)&bS[h0];
    float4 b1 = *(const float4*)&bS[h0 + 4];
    float bias[8] = {b0.x, b0.y, b0.z, b0.w, b1.x, b1.y, b1.z, b1.w};
    unsigned int* XsT32 = (unsigned int*)XsT;   // pitch 68 uints per k row

    for (int tile = tile0; tile < ntiles; tile += stride) {
        int node0 = tile * 128;
        __syncthreads();   // prev-iter reads done; W visible on first iter
        for (int it = tid; it < 512; it += 256) {
            int p = it & 63, c = it >> 6;
            int g0 = node0 + 2 * p, g1 = g0 + 1;
            uint4 av = make_uint4(0, 0, 0, 0), bv = make_uint4(0, 0, 0, 0);
            if (g0 < n) av = *(const uint4*)(X + (size_t)g0 * 64 + c * 8);
            if (g1 < n) bv = *(const uint4*)(X + (size_t)g1 * 64 + c * 8);
            unsigned int aw[4] = {av.x, av.y, av.z, av.w};
            unsigned int bw[4] = {bv.x, bv.y, bv.z, bv.w};
#pragma unroll
            for (int j = 0; j < 8; ++j) {
                int w = j >> 1;
                unsigned int o = (j & 1)
                    ? ((aw[w] >> 16) | (bw[w] & 0xFFFF0000u))
                    : ((aw[w] & 0xFFFFu) | (bw[w] << 16));
                XsT32[(c * 8 + j) * 68 + p] = o;
            }
        }
        __syncthreads();
        float accA[4][8], accS[4][8];
#pragma unroll
        for (int r = 0; r < 4; ++r)
#pragma unroll
            for (int c = 0; c < 8; ++c) { accA[r][c] = 0.0f; accS[r][c] = 0.0f; }
#pragma unroll 4
        for (int k = 0; k < 64; ++k) {
            ushort4 xv = *(const ushort4*)(XsT + k * 136 + nA);
            float xr[4] = {b2f(xv.x), b2f(xv.y), b2f(xv.z), b2f(xv.w)};
            float4 a0 = *(const float4*)&WA[k * 64 + h0];
            float4 a1 = *(const float4*)&WA[k * 64 + h0 + 4];
            float4 s0 = *(const float4*)&WS[k * 64 + h0];
            float4 s1 = *(const float4*)&WS[k * 64 + h0 + 4];
            float wa[8] = {a0.x, a0.y, a0.z, a0.w, a1.x, a1.y, a1.z, a1.w};
            float ws[8] = {s0.x, s0.y, s0.z, s0.w, s1.x, s1.y, s1.z, s1.w};
#pragma unroll
            for (int r = 0; r < 4; ++r)
#pragma unroll
                for (int c = 0; c < 8; ++c) {
                    accA[r][c] += xr[r] * wa[c];
                    accS[r][c] += xr[r] * ws[c];
                }
        }
#pragma unroll
        for (int r = 0; r < 4; ++r) {
            int gi = node0 + nA + r;
            if (gi < n) {
                uint4 oa, os;
                oa.x = pk2(accA[r][0], accA[r][1]); oa.y = pk2(accA[r][2], accA[r][3]);
                oa.z = pk2(accA[r][4], accA[r][5]); oa.w = pk2(accA[r][6], accA[r][7]);
                os.x = pk2(accS[r][0] + bias[0], accS[r][1] + bias[1]);
                os.y = pk2(accS[r][2] + bias[2], accS[r][3] + bias[3]);
                os.z = pk2(accS[r][4] + bias[4], accS[r][5] + bias[5]);
                os.w = pk2(accS[r][6] + bias[6], accS[r][7] + bias[7]);
                *(uint4*)(A + (size_t)gi * 64 + h0) = oa;
                *(uint4*)(S + (size_t)gi * 64 + h0) = os;
            }
        }
    }
}

// ---- fine CSR body --------------------------------------------------------

template <int NPB, int SH, typename CT>
__device__ __forceinline__ void fine_body(
    int b, int* c, int* sc, const int* __restrict__ part,
    const int* __restrict__ cnt_arr,
    int2* __restrict__ rp2, CT* __restrict__ col, int n) {
    int cnt = min(cnt_arr[b], BC);
    int pb = b * BC;
    int t = threadIdx.x;
    c[t] = 0;
    __syncthreads();
    const int mask = NPB - 1;
    for (int j = t; j < cnt; j += 256)
        atomicAdd(&c[part[pb + j] & mask], 1);
    __syncthreads();
    int own = c[t];
    sc[t] = own;
    __syncthreads();
    for (int off = 1; off < 256; off <<= 1) {
        int val = sc[t];
        int add = (t >= off) ? sc[t - off] : 0;
        __syncthreads();
        sc[t] = val + add;
        __syncthreads();
    }
    int start = pb + sc[t] - own;
    int node = b * NPB + t;
    if (t < NPB && node < n) rp2[node] = make_int2(start, start + own);
    __syncthreads();
    c[t] = start;
    __syncthreads();
    for (int j = t; j < cnt; j += 256) {
        int p = part[pb + j];
        int off = atomicAdd(&c[p & mask], 1);
        col[off] = (CT)(((unsigned)p) >> SH);
    }
}

#define TBM 256   // movie transform blocks
#define TBU 512   // user transform blocks
#define SMEMF (4352 + 4096 + 4096)   // floats: XsT 17408 B + WA 16 KB + WS 16 KB = 50176 B

// ---- build_b: [0, nbm+nbu) fine CSR | +TBM movie transform | +TBU user ----

__global__ __launch_bounds__(256) void build_b(
    int nbm, int nbu, int ntm, int ntu,
    const int* __restrict__ pm, const int* __restrict__ cm,
    int2* __restrict__ rp2_m, int* __restrict__ col_m, int M,
    const int* __restrict__ pu, const int* __restrict__ cu,
    int2* __restrict__ rp2_u, unsigned short* __restrict__ col_u, int U,
    const unsigned short* __restrict__ xM, const float* __restrict__ wAM,
    const float* __restrict__ wSM, const float* __restrict__ bSM,
    unsigned short* __restrict__ AM, unsigned short* __restrict__ SM,
    const unsigned short* __restrict__ xU, const float* __restrict__ wAU,
    const float* __restrict__ wSU, const float* __restrict__ bSU,
    unsigned short* __restrict__ AU, unsigned short* __restrict__ SU) {
    __shared__ float smem[SMEMF];
    int b = blockIdx.x;
    if (b < nbm) {
        fine_body<128, 7, int>(b, (int*)smem, (int*)smem + 256, pm, cm, rp2_m, col_m, M);
        return;
    }
    b -= nbm;
    if (b < nbu) {
        fine_body<256, 8, unsigned short>(b, (int*)smem, (int*)smem + 256, pu, cu, rp2_u, col_u, U);
        return;
    }
    b -= nbu;
    unsigned short* XsT = (unsigned short*)smem;
    float* WA = smem + 4352; float* WS = WA + 4096;
    if (b < TBM) transform_tiles(b, TBM, ntm, XsT, WA, WS, xM, wAM, wSM, bSM, AM, SM, M);
    else transform_tiles(b - TBM, TBU, ntu, XsT, WA, WS, xU, wAU, wSU, bSU, AU, SU, U);
}

// ---- standalone transform (layer 1) ---------------------------------------

__global__ __launch_bounds__(256) void transform_dual(
    int ntm, int ntu,
    const unsigned short* __restrict__ xM, const float* __restrict__ wAM,
    const float* __restrict__ wSM, const float* __restrict__ bSM,
    unsigned short* __restrict__ AM, unsigned short* __restrict__ SM, int M,
    const unsigned short* __restrict__ xU, const float* __restrict__ wAU,
    const float* __restrict__ wSU, const float* __restrict__ bSU,
    unsigned short* __restrict__ AU, unsigned short* __restrict__ SU, int U) {
    __shared__ float smem[SMEMF];
    unsigned short* XsT = (unsigned short*)smem;
    float* WA = smem + 4352; float* WS = WA + 4096;
    int b = blockIdx.x;
    if (b < TBM) transform_tiles(b, TBM, ntm, XsT, WA, WS, xM, wAM, wSM, bSM, AM, SM, M);
    else transform_tiles(b - TBM, TBU, ntu, XsT, WA, WS, xU, wAU, wSU, bSU, AU, SU, U);
}

// ---- dual gather: 8 groups x 8 lanes, uint4 rows --------------------------

template <typename CT>
__device__ __forceinline__ void gather_body(
    int b, const int2* __restrict__ rp2, const CT* __restrict__ col,
    const unsigned short* __restrict__ A, const unsigned short* __restrict__ S,
    unsigned short* __restrict__ out, int n, int do_relu) {
    int node = (b * 256 + threadIdx.x) >> 6;
    if (node >= n) return;
    int lane = threadIdx.x & 63;
    int g = lane >> 3, q = lane & 7;     // 8 neighbor-groups x 8 feature-lanes
    int2 be = rp2[node];
    int beg = be.x, end = be.y;
    float s0 = 0, s1 = 0, s2 = 0, s3 = 0, s4 = 0, s5 = 0, s6 = 0, s7 = 0;
    float t0 = 0, t1 = 0, t2 = 0, t3 = 0, t4 = 0, t5 = 0, t6 = 0, t7 = 0;
    int j = beg + g;
    for (; j + 8 < end; j += 16) {
        int n0 = (int)col[j], n1 = (int)col[j + 8];
        uint4 w0 = *(const uint4*)(A + (size_t)n0 * 64 + q * 8);
        uint4 w1 = *(const uint4*)(A + (size_t)n1 * 64 + q * 8);
        float2 p;
        p = bf2(w0.x); s0 += p.x; s1 += p.y;
        p = bf2(w0.y); s2 += p.x; s3 += p.y;
        p = bf2(w0.z); s4 += p.x; s5 += p.y;
        p = bf2(w0.w); s6 += p.x; s7 += p.y;
        p = bf2(w1.x); t0 += p.x; t1 += p.y;
        p = bf2(w1.y); t2 += p.x; t3 += p.y;
        p = bf2(w1.z); t4 += p.x; t5 += p.y;
        p = bf2(w1.w); t6 += p.x; t7 += p.y;
    }
    if (j < end) {
        int n0 = (int)col[j];
        uint4 w0 = *(const uint4*)(A + (size_t)n0 * 64 + q * 8);
        float2 p;
        p = bf2(w0.x); s0 += p.x; s1 += p.y;
        p = bf2(w0.y); s2 += p.x; s3 += p.y;
        p = bf2(w0.z); s4 += p.x; s5 += p.y;
        p = bf2(w0.w); s6 += p.x; s7 += p.y;
    }
    s0 += t0; s1 += t1; s2 += t2; s3 += t3;
    s4 += t4; s5 += t5; s6 += t6; s7 += t7;
#pragma unroll
    for (int off = 8; off < 64; off <<= 1) {
        s0 += __shfl_xor(s0, off, 64); s1 += __shfl_xor(s1, off, 64);
        s2 += __shfl_xor(s2, off, 64); s3 += __shfl_xor(s3, off, 64);
        s4 += __shfl_xor(s4, off, 64); s5 += __shfl_xor(s5, off, 64);
        s6 += __shfl_xor(s6, off, 64); s7 += __shfl_xor(s7, off, 64);
    }
    if (g == 0) {
        float inv = 1.0f / fmaxf((float)(end - beg), 1.0f);
        uint4 sv = *(const uint4*)(S + (size_t)node * 64 + q * 8);
        float2 c0 = bf2(sv.x), c1 = bf2(sv.y), c2 = bf2(sv.z), c3 = bf2(sv.w);
        float v0 = s0 * inv + c0.x, v1 = s1 * inv + c0.y;
        float v2 = s2 * inv + c1.x, v3 = s3 * inv + c1.y;
        float v4 = s4 * inv + c2.x, v5 = s5 * inv + c2.y;
        float v6 = s6 * inv + c3.x, v7 = s7 * inv + c3.y;
        if (do_relu) {
            v0 = fmaxf(v0, 0.f); v1 = fmaxf(v1, 0.f); v2 = fmaxf(v2, 0.f);
            v3 = fmaxf(v3, 0.f); v4 = fmaxf(v4, 0.f); v5 = fmaxf(v5, 0.f);
            v6 = fmaxf(v6, 0.f); v7 = fmaxf(v7, 0.f);
        }
        uint4 o;
        o.x = pk2(v0, v1); o.y = pk2(v2, v3); o.z = pk2(v4, v5); o.w = pk2(v6, v7);
        *(uint4*)(out + (size_t)node * 64 + q * 8) = o;
    }
}

__global__ __launch_bounds__(256) void gather_dual(
    int gm,
    const int2* __restrict__ rp2_m, const int* __restrict__ col_m,
    const unsigned short* __restrict__ AU, const unsigned short* __restrict__ SM,
    unsigned short* __restrict__ outM, int M,
    const int2* __restrict__ rp2_u, const unsigned short* __restrict__ col_u,
    const unsigned short* __restrict__ AM, const unsigned short* __restrict__ SU,
    unsigned short* __restrict__ outU, int U, int do_relu) {
    int b = blockIdx.x;
    if (b < gm) gather_body<int>(b, rp2_m, col_m, AU, SM, outM, M, do_relu);
    else gather_body<unsigned short>(b - gm, rp2_u, col_u, AM, SU, outU, U, do_relu);
}

// ---- link head: 8 edges/wave, uint4 lanes ---------------------------------

__global__ __launch_bounds__(256) void dot_bf16(
    const int* __restrict__ ls, const int* __restrict__ ld,
    const unsigned short* __restrict__ xuB, const unsigned short* __restrict__ xmB,
    float* __restrict__ out, int L) {
    int t = blockIdx.x * 256 + threadIdx.x;
    int lane = t & 63;
    int sub = lane >> 3, q = lane & 7;
    int e = (t >> 6) * 8 + sub;
    if (e < L) {
        int u = ls[e], m = ld[e];
        uint4 a = *(const uint4*)(xuB + (size_t)u * 64 + q * 8);
        uint4 b = *(const uint4*)(xmB + (size_t)m * 64 + q * 8);
        float2 a0 = bf2(a.x), a1 = bf2(a.y), a2 = bf2(a.z), a3 = bf2(a.w);
        float2 b0 = bf2(b.x), b1 = bf2(b.y), b2 = bf2(b.z), b3 = bf2(b.w);
        float p = a0.x * b0.x + a0.y * b0.y + a1.x * b1.x + a1.y * b1.y
                + a2.x * b2.x + a2.y * b2.y + a3.x * b3.x + a3.y * b3.y;
#pragma unroll
        for (int off = 1; off < 8; off <<= 1) p += __shfl_xor(p, off, 64);
        if (q == 0) out[e] = p;
    }
}

// ---------------------------------------------------------------------------

extern "C" void kernel_launch(void* const* d_in, const int* in_sizes, int n_in,
                              void* d_out, int out_size, void* d_ws, size_t ws_size,
                              hipStream_t stream) {
    const float* movie_x   = (const float*)d_in[0];
    const float* user_emb  = (const float*)d_in[1];
    const float* movie_emb = (const float*)d_in[2];
    const float* mlw       = (const float*)d_in[3];
    const float* mlb       = (const float*)d_in[4];
    const float* llw       = (const float*)d_in[5];   // [2][2][64][64]
    const float* llb       = (const float*)d_in[6];   // [2][2][64]
    const float* lrw       = (const float*)d_in[7];   // [2][2][64][64]
    const int*   esrc      = (const int*)d_in[8];
    const int*   edst      = (const int*)d_in[9];
    const int*   lsrc      = (const int*)d_in[10];
    const int*   ldst      = (const int*)d_in[11];

    const int U = in_sizes[1] / 64;
    const int M = in_sizes[2] / 64;
    const int E = in_sizes[8];
    const int L = in_sizes[10];
    float* out = (float*)d_out;

    const size_t M64 = (size_t)M * 64, U64 = (size_t)U * 64;
    const int nbu = (U + 255) >> 8;   // 256-user buckets  (391)
    const int nbm = (M + 127) >> 7;   // 128-movie buckets (391)

    // ---- ws layout: 256 B-aligned regions, hot tables first ----
    char* base = (char*)d_ws;
    size_t off = 0;
    auto alloc = [&](size_t bytes) -> void* {
        off = (off + 255) & ~(size_t)255;
        void* p = base + off;
        off += bytes;
        return p;
    };
    unsigned short* bmB0 = (unsigned short*)alloc(M64 * 2);   // movie feat L0 bf16
    unsigned short* buB0 = (unsigned short*)alloc(U64 * 2);   // user feat L0 bf16
    unsigned short* A_m  = (unsigned short*)alloc(M64 * 2);   // bf16, gathered by users
    unsigned short* A_u  = (unsigned short*)alloc(U64 * 2);   // bf16, gathered by movies
    unsigned short* S_m  = (unsigned short*)alloc(M64 * 2);   // bf16 self term
    unsigned short* S_u  = (unsigned short*)alloc(U64 * 2);
    unsigned short* xm1  = (unsigned short*)alloc(M64 * 2);   // layer-0 movie out
    unsigned short* xu1  = (unsigned short*)alloc(U64 * 2);   // layer-0 user out
    float* wTl = (float*)alloc(4 * 4096 * 4);
    float* wTr = (float*)alloc(4 * 4096 * 4);
    int2* rp2_m = (int2*)alloc((size_t)M * 8);
    int2* rp2_u = (int2*)alloc((size_t)U * 8);
    int* col_m = (int*)alloc((size_t)nbm * BC * 4);           // padded, user ids
    unsigned short* col_u = (unsigned short*)alloc((size_t)nbu * BC * 2);
    int* bfu = (int*)alloc(800 * 4);                          // ONE region: bfu|bfm
    int* bfm = bfu + 400;
    int* part_u = (int*)alloc((size_t)nbu * BC * 4);          // packed 24-bit
    int* part_m = (int*)alloc((size_t)nbm * BC * 4);
    // final tables alias the (dead-by-then) part buffers (contiguous, aligned):
    unsigned short* xm2 = (unsigned short*)part_u;            // [M,64] final movie
    unsigned short* xu2 = xm2 + M64;                          // [U,64] final user

    const int np    = (E + CHP - 1) / CHP;                    // dual-dir chunks
    const int cvtb  = (U * 16 / 4 + 255) / 256;               // 4 float4/thread
    const int ntm = (M + 127) / 128, ntu = (U + 127) / 128;   // 128-node tiles
    const int gm_g = (M * 64 + 255) / 256, gu_g = (U * 64 + 255) / 256;

    // ---- build_a: dual-dir register partition + prep (fused) ----
    hipMemsetAsync(bfu, 0, 800 * sizeof(int), stream);
    build_a<<<np + 1088 + cvtb, 256, 0, stream>>>(
        np, esrc, edst, E, nbu, nbm, bfu, bfm, part_u, part_m,
        movie_x, mlw, mlb, movie_emb, bmB0, M,
        llw, lrw, wTl, wTr, user_emb, buB0, U * 16);

    // ---- build_b: fine CSR + transform L0 (fused) ----
    build_b<<<nbm + nbu + TBM + TBU, 256, 0, stream>>>(
        nbm, nbu, ntm, ntu,
        part_m, bfm, rp2_m, col_m, M,
        part_u, bfu, rp2_u, col_u, U,
        bmB0, wTl + 1 * 4096, wTr + 0 * 4096, llb + 0 * 64, A_m, S_m,
        buB0, wTl + 0 * 4096, wTr + 1 * 4096, llb + 1 * 64, A_u, S_u);

    // ---- layer 0 gather ----
    gather_dual<<<gm_g + gu_g, 256, 0, stream>>>(gm_g,
        rp2_m, col_m, A_u, S_m, xm1, M,
        rp2_u, col_u, A_m, S_u, xu1, U, 1);

    // ---- layer 1 ---- (A/S reused; part buffers now dead -> xm2/xu2)
    transform_dual<<<TBM + TBU, 256, 0, stream>>>(ntm, ntu,
        xm1, wTl + 3 * 4096, wTr + 2 * 4096, llb + 2 * 64, A_m, S_m, M,
        xu1, wTl + 2 * 4096, wTr + 3 * 4096, llb + 3 * 64, A_u, S_u, U);
    gather_dual<<<gm_g + gu_g, 256, 0, stream>>>(gm_g,
        rp2_m, col_m, A_u, S_m, xm2, M,
        rp2_u, col_u, A_m, S_u, xu2, U, 0);

    // ---- link head ----
    dot_bf16<<<(L + 31) / 32, 256, 0, stream>>>(lsrc, ldst, xu2, xm2, out, L);
}